// Round 1
// baseline (65.565 us; speedup 1.0000x reference)
//
#include <hip/hip_runtime.h>
#include <hip/hip_bf16.h>

// Renderer interpolation: out[p, d] = sum_k bary[p,k] * attributes[faces[wrap(pix[p])][k], d]
// mask[p] = (pix[p] != -1)
// H=W=1024, D=32, F=100000, V=50000. 8 threads per pixel, float4 per thread.

__global__ __launch_bounds__(256) void Renderer_interp_kernel(
    const int* __restrict__ pix,      // (H*W)
    const float* __restrict__ bary,   // (H*W, 3)
    const int* __restrict__ faces,    // (F, 3)
    const float* __restrict__ attr,   // (V, 32)
    float* __restrict__ out,          // (H*W, 32)
    float* __restrict__ mask,         // (H*W) as float 0/1
    int npix, int F)
{
    int tid = blockIdx.x * blockDim.x + threadIdx.x;
    int p = tid >> 3;      // pixel index
    int t = tid & 7;       // d-chunk index: handles d = 4t .. 4t+3
    if (p >= npix) return;

    int fraw = pix[p];
    int f = (fraw < 0) ? (fraw + F) : fraw;   // mode='wrap': -1 -> F-1

    int base = 3 * f;
    int v0 = faces[base + 0];
    int v1 = faces[base + 1];
    int v2 = faces[base + 2];

    float w0 = bary[3 * p + 0];
    float w1 = bary[3 * p + 1];
    float w2 = bary[3 * p + 2];

    const float4* A = reinterpret_cast<const float4*>(attr);
    float4 r0 = A[v0 * 8 + t];
    float4 r1 = A[v1 * 8 + t];
    float4 r2 = A[v2 * 8 + t];

    float4 o;
    o.x = w0 * r0.x + w1 * r1.x + w2 * r2.x;
    o.y = w0 * r0.y + w1 * r1.y + w2 * r2.y;
    o.z = w0 * r0.z + w1 * r1.z + w2 * r2.z;
    o.w = w0 * r0.w + w1 * r1.w + w2 * r2.w;

    reinterpret_cast<float4*>(out)[p * 8 + t] = o;

    if (t == 0) {
        mask[p] = (fraw != -1) ? 1.0f : 0.0f;
    }
}

extern "C" void kernel_launch(void* const* d_in, const int* in_sizes, int n_in,
                              void* d_out, int out_size, void* d_ws, size_t ws_size,
                              hipStream_t stream) {
    const int*   pix   = (const int*)d_in[0];
    const float* bary  = (const float*)d_in[1];
    const int*   faces = (const int*)d_in[2];
    const float* attr  = (const float*)d_in[3];

    int npix = in_sizes[0];        // H*W = 1048576
    int F    = in_sizes[2] / 3;    // 100000

    float* out  = (float*)d_out;           // (npix, 32)
    float* mask = (float*)d_out + (size_t)npix * 32;  // (npix,)

    int total = npix * 8;
    int block = 256;
    int grid = (total + block - 1) / block;
    Renderer_interp_kernel<<<grid, block, 0, stream>>>(pix, bary, faces, attr,
                                                       out, mask, npix, F);
}